// Round 7
// baseline (43.518 us; speedup 1.0000x reference)
//
#include <hip/hip_runtime.h>
#include <hip/hip_bf16.h>

#define N_TOK 65536
#define DIM 64
#define K_CODES 1024
#define MAGIC 0xC0FFEE42u

typedef short short8 __attribute__((ext_vector_type(8)));
typedef __bf16 bf16x8 __attribute__((ext_vector_type(8)));
typedef float f32x4 __attribute__((ext_vector_type(4)));
typedef unsigned uintx4 __attribute__((ext_vector_type(4)));

static __device__ __forceinline__ short cvt_bf16(float x) {
    return __builtin_bit_cast(short, __float2bfloat16(x));
}

// Bank-conflict swizzle for the 128 KB B-tile: permutes 16B chunks within each
// 2 KB window. Applied to BOTH the staging ds_write and the K-loop ds_read.
static __device__ __forceinline__ int swz(int byte_off) {
    return byte_off ^ (((byte_off >> 8) & 7) << 4);
}

// Single-dispatch fused kernel: 256 blocks x 1024 threads (16 waves, 1 block/CU).
// Wave (rg = w>>2, h = w&3): rows rg*64..+63 vs code tiles h*16..+15.
// B-fragments in LDS (swizzled): frag f = ti*2 + s holds B[k][col] =
// emb[ti*16 + (lane&15)][s*32 + (lane>>4)*8 + j] at swz(f*1024 + lane*16) bytes.
// Argmin maximizes tv = <l,e>_bf16 + 4 - ||e||^2/2 (> 0), packed with index
// bits under max_u32. Loss: per-block partial published as a self-validating
// pair (w, w^MAGIC) via agent-scope atomics; block 255 wave 0 spin-collects
// all 256 pairs in fixed order and writes the scalar (no second dispatch,
// no grid.sync, no counter init needed -- garbage/poison fails the pair check,
// stale pairs from a previous replay hold identical values by determinism).
__global__ __launch_bounds__(1024, 4) void vq_main(const float* __restrict__ lat,
                                                   const float* __restrict__ emb,
                                                   float* __restrict__ out,
                                                   unsigned* __restrict__ pairs) {
    __shared__ __align__(16) short lds_b[65536];      // 128 KB
    __shared__ float lds_cv[K_CODES];                 // 4 KB
    __shared__ __align__(16) unsigned lds_comb[1024]; // [row][h]
    __shared__ int lds_code[256];
    __shared__ float lds_lnp[16];
    __shared__ float lds_rl[4];

    const int tid  = threadIdx.x;
    const int lane = tid & 63;
    const int wave = tid >> 6;
    const int rg = wave >> 2;
    const int h  = wave & 3;
    const int c = lane & 15;
    const int g = lane >> 4;
    const int wrow0 = blockIdx.x * 256 + rg * 64;
    char* lds_bc = reinterpret_cast<char*>(lds_b);

    // A-fragments (4 m-tiles of 16 rows) + exact f32 ||l||^2 partial.
    bf16x8 a[4][2];
    float lnp = 0.f;
#pragma unroll
    for (int m = 0; m < 4; ++m) {
        const f32x4* rp4 = reinterpret_cast<const f32x4*>(lat + (size_t)(wrow0 + m * 16 + c) * DIM);
        f32x4 p0 = rp4[g * 2], p1 = rp4[g * 2 + 1];
        f32x4 p2 = rp4[8 + g * 2], p3 = rp4[8 + g * 2 + 1];
        short8 t0, t1;
#pragma unroll
        for (int j = 0; j < 4; ++j) {
            lnp = fmaf(p0[j], p0[j], lnp); lnp = fmaf(p1[j], p1[j], lnp);
            lnp = fmaf(p2[j], p2[j], lnp); lnp = fmaf(p3[j], p3[j], lnp);
            t0[j] = cvt_bf16(p0[j]); t0[4 + j] = cvt_bf16(p1[j]);
            t1[j] = cvt_bf16(p2[j]); t1[4 + j] = cvt_bf16(p3[j]);
        }
        a[m][0] = __builtin_bit_cast(bf16x8, t0);
        a[m][1] = __builtin_bit_cast(bf16x8, t1);
    }
#pragma unroll
    for (int off = 1; off < 64; off <<= 1) lnp += __shfl_xor(lnp, off, 64);
    if (lane == 0) lds_lnp[wave] = lnp;

    // Stage + convert codebook: unit u = (code = u>>3, dims (u&7)*8..+7).
    // Coalesced 32B f32 reads; 8-lane shfl groups reduce code norms in-flight.
#pragma unroll
    for (int i = 0; i < 8; ++i) {
        const int u = i * 1024 + tid;
        const int code = u >> 3, d0 = (u & 7) * 8;
        f32x4 q0 = *reinterpret_cast<const f32x4*>(emb + (size_t)u * 8);
        f32x4 q1 = *reinterpret_cast<const f32x4*>(emb + (size_t)u * 8 + 4);
        float ns = 0.f;
        short8 v;
#pragma unroll
        for (int j = 0; j < 4; ++j) {
            ns = fmaf(q0[j], q0[j], ns); ns = fmaf(q1[j], q1[j], ns);
            v[j] = cvt_bf16(q0[j]); v[4 + j] = cvt_bf16(q1[j]);
        }
        ns += __shfl_xor(ns, 1, 64);
        ns += __shfl_xor(ns, 2, 64);
        ns += __shfl_xor(ns, 4, 64);
        const int f  = (code >> 4) * 2 + (d0 >> 5);
        const int lt = (code & 15) + ((d0 & 31) >> 3) * 16;
        *reinterpret_cast<short8*>(lds_bc + swz(f * 1024 + lt * 16)) = v;
        if ((u & 7) == 0) lds_cv[code] = 4.0f - 0.5f * ns;
    }

    unsigned pm[4][4];
#pragma unroll
    for (int m = 0; m < 4; ++m)
#pragma unroll
        for (int j = 0; j < 4; ++j) pm[m][j] = 0u;

    const int bbyte = h * 32768 + lane * 16;   // base byte of this wave's B reads
    __syncthreads();

#pragma unroll 4
    for (int ti = 0; ti < 16; ++ti) {
        bf16x8 b0 = __builtin_bit_cast(bf16x8,
            *reinterpret_cast<const short8*>(lds_bc + swz(bbyte + ti * 2048)));
        bf16x8 b1 = __builtin_bit_cast(bf16x8,
            *reinterpret_cast<const short8*>(lds_bc + swz(bbyte + ti * 2048 + 1024)));
        const float cv = lds_cv[(h * 16 + ti) * 16 + c];
        const unsigned ib = 63u - (unsigned)ti;
#pragma unroll
        for (int m = 0; m < 4; ++m) {
            f32x4 acc = {cv, cv, cv, cv};
            acc = __builtin_amdgcn_mfma_f32_16x16x32_bf16(a[m][0], b0, acc, 0, 0, 0);
            acc = __builtin_amdgcn_mfma_f32_16x16x32_bf16(a[m][1], b1, acc, 0, 0, 0);
#pragma unroll
            for (int j = 0; j < 4; ++j) {
                unsigned ub = __builtin_bit_cast(unsigned, acc[j]);
                unsigned pv = (ub & 0xFFFFFFC0u) | ib;
                pm[m][j] = pm[m][j] < pv ? pv : pm[m][j];
            }
        }
    }

    // per-wave reduce over 16 code-columns; repack with 10-bit global code
#pragma unroll
    for (int m = 0; m < 4; ++m) {
#pragma unroll
        for (int j = 0; j < 4; ++j) {
            unsigned v = pm[m][j];
            unsigned gcode = ((unsigned)h * 16u + (63u - (v & 63u))) * 16u + (unsigned)c;
            v = (v & 0xFFFFFC00u) | (1023u - gcode);
#pragma unroll
            for (int off = 1; off < 16; off <<= 1) {
                unsigned o = (unsigned)__shfl_xor((int)v, off, 64);
                v = v < o ? o : v;
            }
            pm[m][j] = v;
        }
    }
    if (c == 0) {
#pragma unroll
        for (int m = 0; m < 4; ++m)
#pragma unroll
            for (int j = 0; j < 4; ++j) {
                const int row = rg * 64 + m * 16 + g * 4 + j;
                lds_comb[row * 4 + h] = pm[m][j];
            }
    }
    __syncthreads();

    // combine across h (256 rows); emit winner code + per-row loss term
    if (tid < 256) {
        uintx4 cm = *reinterpret_cast<const uintx4*>(&lds_comb[tid * 4]);
        unsigned v0 = cm[0] > cm[1] ? cm[0] : cm[1];
        unsigned v1 = cm[2] > cm[3] ? cm[2] : cm[3];
        unsigned v = v0 > v1 ? v0 : v1;
        lds_code[tid] = (int)(1023u - (v & 1023u));
        float tv = __builtin_bit_cast(float, v & 0xFFFFFC00u);
        float rl = fmaf(-2.0f, tv, 8.0f);
#pragma unroll
        for (int off = 1; off < 64; off <<= 1) rl += __shfl_xor(rl, off, 64);
        if (lane == 0) lds_rl[wave] = rl;
    }
    __syncthreads();

    // coalesced output gather: 256 rows x 64 f32 dims as 16B chunks
#pragma unroll
    for (int it = 0; it < 4; ++it) {
        const int cidx = it * 1024 + tid;
        const int row = cidx >> 4, seg = cidx & 15;
        const int gc = lds_code[row];
        reinterpret_cast<f32x4*>(out)[(size_t)(blockIdx.x * 256 + row) * 16 + seg] =
            reinterpret_cast<const f32x4*>(emb)[(size_t)gc * 16 + seg];
    }

    // publish this block's loss partial as a self-validating pair
    if (tid == 0) {
        float part = lds_rl[0] + lds_rl[1] + lds_rl[2] + lds_rl[3]
                   + lds_lnp[0] + lds_lnp[4] + lds_lnp[8] + lds_lnp[12];
        unsigned w0 = __builtin_bit_cast(unsigned, part);
        __hip_atomic_store(&pairs[blockIdx.x * 2], w0,
                           __ATOMIC_RELEASE, __HIP_MEMORY_SCOPE_AGENT);
        __hip_atomic_store(&pairs[blockIdx.x * 2 + 1], w0 ^ MAGIC,
                           __ATOMIC_RELEASE, __HIP_MEMORY_SCOPE_AGENT);
    }

    // block 255, wave 0: spin-collect all 256 pairs (fixed order -> deterministic)
    if (blockIdx.x == 255 && wave == 0) {
        float s[4];
#pragma unroll
        for (int q = 0; q < 4; ++q) {
            const int b = lane * 4 + q;
            unsigned w0, w1;
            do {
                w0 = __hip_atomic_load(&pairs[b * 2],
                                       __ATOMIC_ACQUIRE, __HIP_MEMORY_SCOPE_AGENT);
                w1 = __hip_atomic_load(&pairs[b * 2 + 1],
                                       __ATOMIC_ACQUIRE, __HIP_MEMORY_SCOPE_AGENT);
                if (w1 != (w0 ^ MAGIC)) __builtin_amdgcn_s_sleep(2);
            } while (w1 != (w0 ^ MAGIC));
            s[q] = __builtin_bit_cast(float, w0);
        }
        float p = (s[0] + s[1]) + (s[2] + s[3]);
#pragma unroll
        for (int off = 1; off < 64; off <<= 1) p += __shfl_xor(p, off, 64);
        if (lane == 0)
            out[(size_t)N_TOK * DIM] = p * (1.25f / 4194304.f);
    }
}

extern "C" void kernel_launch(void* const* d_in, const int* in_sizes, int n_in,
                              void* d_out, int out_size, void* d_ws, size_t ws_size,
                              hipStream_t stream) {
    const float* lat = (const float*)d_in[0];
    const float* emb = (const float*)d_in[1];
    float* out = (float*)d_out;
    unsigned* pairs = (unsigned*)d_ws;

    vq_main<<<256, 1024, 0, stream>>>(lat, emb, out, pairs);
}

// Round 8
// 30.353 us; speedup vs baseline: 1.4337x; 1.4337x over previous
//
#include <hip/hip_runtime.h>
#include <hip/hip_bf16.h>

#define N_TOK 65536
#define DIM 64
#define K_CODES 1024

typedef float f32x4 __attribute__((ext_vector_type(4)));
typedef int   i32x2 __attribute__((ext_vector_type(2)));
typedef unsigned uintx4 __attribute__((ext_vector_type(4)));

// pack 4 f32 -> 4 OCP e4m3 bytes (little-endian order a,b,c,d)
static __device__ __forceinline__ int pk_fp8x4(float a, float b, float c, float d) {
    int v = __builtin_amdgcn_cvt_pk_fp8_f32(a, b, 0, false);
    v = __builtin_amdgcn_cvt_pk_fp8_f32(c, d, v, true);
    return v;
}
static __device__ __forceinline__ long pk_fp8x8(f32x4 x, f32x4 y) {
    i32x2 t;
    t[0] = pk_fp8x4(x[0], x[1], x[2], x[3]);
    t[1] = pk_fp8x4(y[0], y[1], y[2], y[3]);
    return __builtin_bit_cast(long, t);
}

// LDS swizzle for the 64 KB fp8 B-tile: XOR addr bits [9:7] into [6:4].
// Bijective per 128-B window; applied to both ds_write (staging) and ds_read.
static __device__ __forceinline__ int swz8(int byte_off) {
    return byte_off ^ (((byte_off >> 7) & 7) << 4);
}

// Main: 512 blocks x 1024 threads (16 waves). LDS ~72 KB -> 2 blocks/CU for
// cross-block phase overlap. Block covers 128 rows. Wave (rg = w>>2, h = w&3):
// rows rg*32..+31 (2 m-tiles) vs code quarter h (16 tiles of 16 codes).
// B-tile fp8 (emb * 2048, e4m3): frag f = tile*2 + s holds B[k][col] =
// 2048*emb[tile*16 + (lane&15)][s*32 + (lane>>4)*8 + j] at swz8(f*512+lane*8).
// Argmin maximizes tv = <l, 2048 e> + 2048*(4 - ||e||^2/2)  (> 0), packed with
// index bits under max_u32 (4 tile bits in-loop, 10 code bits at combine).
// Loss row term = 8 - tv/1024 + ||l||^2 (exact f32 cv/lnp; fp8 dot noise
// ~2e-4 in score units -- far inside the 0.025 threshold).
__global__ __launch_bounds__(1024, 8) void vq_main(const float* __restrict__ lat,
                                                   const float* __restrict__ emb,
                                                   float* __restrict__ out,
                                                   float* __restrict__ partials) {
    __shared__ __align__(16) char lds_b[65536];       // 64 KB fp8 B-tile
    __shared__ float lds_cv[K_CODES];                 // 4 KB
    __shared__ __align__(16) unsigned lds_comb[512];  // [row 0..127][h]
    __shared__ int lds_code[128];
    __shared__ float lds_lnp[16];
    __shared__ float lds_rl[2];

    const int tid  = threadIdx.x;
    const int lane = tid & 63;
    const int wave = tid >> 6;
    const int rg = wave >> 2;
    const int h  = wave & 3;
    const int c = lane & 15;
    const int g = lane >> 4;
    const int wrow0 = blockIdx.x * 128 + rg * 32;

    // A-fragments (2 m-tiles of 16 rows) as fp8 + exact f32 ||l||^2 partial
    long a[2][2];
    float lnp = 0.f;
#pragma unroll
    for (int m = 0; m < 2; ++m) {
        const f32x4* rp4 = reinterpret_cast<const f32x4*>(lat + (size_t)(wrow0 + m * 16 + c) * DIM);
        f32x4 p0 = rp4[g * 2], p1 = rp4[g * 2 + 1];
        f32x4 p2 = rp4[8 + g * 2], p3 = rp4[8 + g * 2 + 1];
#pragma unroll
        for (int j = 0; j < 4; ++j) {
            lnp = fmaf(p0[j], p0[j], lnp); lnp = fmaf(p1[j], p1[j], lnp);
            lnp = fmaf(p2[j], p2[j], lnp); lnp = fmaf(p3[j], p3[j], lnp);
        }
        a[m][0] = pk_fp8x8(p0, p1);
        a[m][1] = pk_fp8x8(p2, p3);
    }
#pragma unroll
    for (int off = 1; off < 64; off <<= 1) lnp += __shfl_xor(lnp, off, 64);
    if (lane == 0) lds_lnp[wave] = lnp;   // rows counted once via h==0 waves

    // Stage + convert codebook (scaled x2048 into e4m3 range); 8-lane shfl
    // groups reduce exact f32 code norms in-flight.
#pragma unroll
    for (int i = 0; i < 8; ++i) {
        const int u = i * 1024 + tid;            // 0..8191
        const int code = u >> 3, d0 = (u & 7) * 8;
        f32x4 q0 = *reinterpret_cast<const f32x4*>(emb + (size_t)u * 8);
        f32x4 q1 = *reinterpret_cast<const f32x4*>(emb + (size_t)u * 8 + 4);
        float ns = 0.f;
#pragma unroll
        for (int j = 0; j < 4; ++j) { ns = fmaf(q0[j], q0[j], ns); ns = fmaf(q1[j], q1[j], ns); }
        ns += __shfl_xor(ns, 1, 64);
        ns += __shfl_xor(ns, 2, 64);
        ns += __shfl_xor(ns, 4, 64);
        i32x2 v;
        v[0] = pk_fp8x4(q0[0] * 2048.f, q0[1] * 2048.f, q0[2] * 2048.f, q0[3] * 2048.f);
        v[1] = pk_fp8x4(q1[0] * 2048.f, q1[1] * 2048.f, q1[2] * 2048.f, q1[3] * 2048.f);
        const int f  = (code >> 4) * 2 + (d0 >> 5);
        const int lt = (code & 15) + ((d0 & 31) >> 3) * 16;
        *reinterpret_cast<i32x2*>(lds_b + swz8(f * 512 + lt * 8)) = v;
        if ((u & 7) == 0) lds_cv[code] = 8192.0f - 1024.0f * ns;   // 2048*(4 - ns/2)
    }

    unsigned pm[2][4];
#pragma unroll
    for (int m = 0; m < 2; ++m)
#pragma unroll
        for (int j = 0; j < 4; ++j) pm[m][j] = 0u;

    const int bbase = h * 16384;   // this wave's code-quarter: 32 frags x 512 B
    __syncthreads();

#pragma unroll 4
    for (int ti = 0; ti < 16; ++ti) {
        long b0 = *reinterpret_cast<const long*>(lds_b + swz8(bbase + ti * 1024 + lane * 8));
        long b1 = *reinterpret_cast<const long*>(lds_b + swz8(bbase + ti * 1024 + 512 + lane * 8));
        const float cv = lds_cv[(h * 16 + ti) * 16 + c];
        f32x4 cvv = {cv, cv, cv, cv};
        const unsigned ib = 15u - (unsigned)ti;
#pragma unroll
        for (int m = 0; m < 2; ++m) {
            f32x4 acc = __builtin_amdgcn_mfma_f32_16x16x32_fp8_fp8(a[m][0], b0, cvv, 0, 0, 0);
            acc = __builtin_amdgcn_mfma_f32_16x16x32_fp8_fp8(a[m][1], b1, acc, 0, 0, 0);
#pragma unroll
            for (int j = 0; j < 4; ++j) {
                unsigned ub = __builtin_bit_cast(unsigned, acc[j]);
                unsigned pv = (ub & 0xFFFFFFF0u) | ib;
                pm[m][j] = pm[m][j] < pv ? pv : pm[m][j];
            }
        }
    }

    // per-wave reduce over 16 code-columns; repack with 10-bit global code
#pragma unroll
    for (int m = 0; m < 2; ++m) {
#pragma unroll
        for (int j = 0; j < 4; ++j) {
            unsigned v = pm[m][j];
            unsigned gcode = ((unsigned)h * 16u + (15u - (v & 15u))) * 16u + (unsigned)c;
            v = (v & 0xFFFFFC00u) | (1023u - gcode);
#pragma unroll
            for (int off = 1; off < 16; off <<= 1) {
                unsigned o = (unsigned)__shfl_xor((int)v, off, 64);
                v = v < o ? o : v;
            }
            pm[m][j] = v;
        }
    }
    if (c == 0) {
#pragma unroll
        for (int m = 0; m < 2; ++m)
#pragma unroll
            for (int j = 0; j < 4; ++j) {
                const int row = rg * 32 + m * 16 + g * 4 + j;   // block-local
                lds_comb[row * 4 + h] = pm[m][j];
            }
    }
    __syncthreads();

    // combine across h (128 rows); emit winner code + per-row loss term
    if (tid < 128) {
        uintx4 cm = *reinterpret_cast<const uintx4*>(&lds_comb[tid * 4]);
        unsigned v0 = cm[0] > cm[1] ? cm[0] : cm[1];
        unsigned v1 = cm[2] > cm[3] ? cm[2] : cm[3];
        unsigned v = v0 > v1 ? v0 : v1;
        lds_code[tid] = (int)(1023u - (v & 1023u));
        float tv = __builtin_bit_cast(float, v & 0xFFFFFC00u);
        float rl = fmaf(-1.0f / 1024.0f, tv, 8.0f);    // 8 - 2*tv_unscaled
#pragma unroll
        for (int off = 1; off < 64; off <<= 1) rl += __shfl_xor(rl, off, 64);
        if (lane == 0) lds_rl[wave] = rl;
    }
    __syncthreads();

    // coalesced output gather: 128 rows x 64 f32 dims as 16B chunks
#pragma unroll
    for (int it = 0; it < 2; ++it) {
        const int cidx = it * 1024 + tid;
        const int row = cidx >> 4, seg = cidx & 15;
        const int gc = lds_code[row];
        reinterpret_cast<f32x4*>(out)[(size_t)(blockIdx.x * 128 + row) * 16 + seg] =
            reinterpret_cast<const f32x4*>(emb)[(size_t)gc * 16 + seg];
    }
    if (tid == 0) {
        partials[blockIdx.x] = lds_rl[0] + lds_rl[1]
                             + lds_lnp[0] + lds_lnp[4] + lds_lnp[8] + lds_lnp[12];
    }
}

// one wave: sum 512 per-block partials (fixed order), scale, write loss scalar
__global__ __launch_bounds__(64) void vq_finalize(const float* __restrict__ partials,
                                                  float* __restrict__ loss_out) {
    const int lane = threadIdx.x;
    f32x4 p4 = reinterpret_cast<const f32x4*>(partials)[lane];
    f32x4 q4 = reinterpret_cast<const f32x4*>(partials)[lane + 64];
    float p = ((p4[0] + p4[1]) + (p4[2] + p4[3]))
            + ((q4[0] + q4[1]) + (q4[2] + q4[3]));
#pragma unroll
    for (int off = 1; off < 64; off <<= 1) p += __shfl_xor(p, off, 64);
    if (lane == 0) loss_out[0] = p * (1.25f / 4194304.f);
}

extern "C" void kernel_launch(void* const* d_in, const int* in_sizes, int n_in,
                              void* d_out, int out_size, void* d_ws, size_t ws_size,
                              hipStream_t stream) {
    const float* lat = (const float*)d_in[0];
    const float* emb = (const float*)d_in[1];
    float* out = (float*)d_out;
    float* partials = (float*)d_ws;

    vq_main<<<512, 1024, 0, stream>>>(lat, emb, out, partials);
    vq_finalize<<<1, 64, 0, stream>>>(partials, out + (size_t)N_TOK * DIM);
}